// Round 17
// baseline (174.199 us; speedup 1.0000x reference)
//
#include <hip/hip_runtime.h>
#include <hip/hip_bf16.h>
#include <stdint.h>

#define Bb 4
#define Nn 2048
#define Dd 1024
#define Hh 16
#define DHd 64
#define Mm (Bb*Nn)     /* 8192 */
#define D3 (3*Dd)      /* 3072 */

typedef unsigned short u16;
typedef unsigned int u32;
typedef __attribute__((ext_vector_type(8))) short bf16x8;
typedef __attribute__((ext_vector_type(4))) float f32x4;
typedef __attribute__((ext_vector_type(16))) float f32x16;
typedef __attribute__((ext_vector_type(4))) unsigned int u32x4;

#define REC_U16 8704               /* per-segment record: 8192 O + 256 f32 m,l */
#define WS_BASE 92274688ull
#define WS_NEED (WS_BASE + 1536ull * REC_U16 * 2)

__device__ __forceinline__ u16 f2bf(float f) {
    unsigned int u = __float_as_uint(f);
    u = (u + 0x7FFFu + ((u >> 16) & 1u)) >> 16;
    return (u16)u;
}
__device__ __forceinline__ float bf2f(u16 v) {
    return __uint_as_float(((u32)v) << 16);
}

__device__ __forceinline__ u32 cvtpk_bf16(float lo, float hi) {
    u32 r;
    asm("v_cvt_pk_bf16_f32 %0, %1, %2" : "=v"(r) : "v"(lo), "v"(hi));
    return r;
}

// bare HW exp2 — no libm guards (inputs bounded by defer-max; -huge underflows to 0)
__device__ __forceinline__ float fexp2(float x) {
    float r;
    asm("v_exp_f32 %0, %1" : "=v"(r) : "v"(x));
    return r;
}

#define GLOAD16(g, l)                                                          \
    __builtin_amdgcn_global_load_lds(                                          \
        (const __attribute__((address_space(1))) unsigned int*)(g),            \
        (__attribute__((address_space(3))) unsigned int*)(l), 16, 0, 0)

// ---------------- fused fp32 -> bf16 convert for all three inputs ----------
__global__ void cvt_all(const float* __restrict__ x, const float* __restrict__ wqkv,
                        const float* __restrict__ wout, u16* __restrict__ xb,
                        u16* __restrict__ wqkvb, u16* __restrict__ woutb, float s) {
    const int A4 = Mm * Dd / 4;
    const int B4 = D3 * Dd / 4;
    const int C4 = Dd * Dd / 4;
    const int QCUT = Dd * Dd / 4;
    const int total = A4 + B4 + C4;
    int i = blockIdx.x * blockDim.x + threadIdx.x;
    const int stride = gridDim.x * blockDim.x;
    for (; i < total; i += stride) {
        const float* src; u16* dst; int j; float sc = 1.f;
        if (i < A4) { src = x; dst = xb; j = i; }
        else if (i < A4 + B4) { j = i - A4; src = wqkv; dst = wqkvb; if (j < QCUT) sc = s; }
        else { j = i - A4 - B4; src = wout; dst = woutb; }
        float4 v = ((const float4*)src)[j];
        u16 o0 = f2bf(v.x * sc), o1 = f2bf(v.y * sc), o2 = f2bf(v.z * sc), o3 = f2bf(v.w * sc);
        ((uint2*)dst)[j] = make_uint2((u32)o0 | ((u32)o1 << 16), (u32)o2 | ((u32)o3 << 16));
    }
}

// ---------------- bf16 GEMM: C[M][N] = A[M][K] * B[N][K]^T ----------------
// 128x128 tile, BK=64, T2 LDS swizzle, T1 XCD swizzle (r13, proven).
template<int OUT_F32>
__global__ __launch_bounds__(256) void gemm_bt(const u16* __restrict__ A,
                                               const u16* __restrict__ Bm,
                                               void* __restrict__ C,
                                               int M, int Nout, int K) {
    __shared__ u16 As[128 * 64];
    __shared__ u16 Bs[128 * 64];
    const int t = threadIdx.x;
    const int lane = t & 63;
    const int w = t >> 6;
    const int wr = w >> 1, wc = w & 1;
    const int l15 = lane & 15, l4 = lane >> 4;

    const int gx = gridDim.x;
    const int linear = blockIdx.y * gx + blockIdx.x;
    const int cpx = (gx * gridDim.y) >> 3;
    const int tile = (linear & 7) * cpx + (linear >> 3);
    const int m0 = (tile / gx) * 128;
    const int n0 = (tile % gx) * 128;

    f32x4 acc[4][4] = {};

    for (int k0 = 0; k0 < K; k0 += 64) {
        __syncthreads();
#pragma unroll
        for (int i = 0; i < 4; i++) {
            int chunk = i * 256 + t;
            int row = chunk >> 3;
            int csw = ((chunk & 7) ^ (row & 7)) << 3;
            GLOAD16(A + (size_t)(m0 + row) * K + k0 + csw, &As[chunk * 8]);
            GLOAD16(Bm + (size_t)(n0 + row) * K + k0 + csw, &Bs[chunk * 8]);
        }
        __syncthreads();

#pragma unroll
        for (int kh = 0; kh < 2; kh++) {
            bf16x8 a[4], b[4];
#pragma unroll
            for (int mi = 0; mi < 4; mi++) {
                int row = wr * 64 + mi * 16 + l15;
                a[mi] = *(const bf16x8*)&As[row * 64 + (((kh * 4 + l4) ^ (row & 7)) << 3)];
            }
#pragma unroll
            for (int nj = 0; nj < 4; nj++) {
                int row = wc * 64 + nj * 16 + l15;
                b[nj] = *(const bf16x8*)&Bs[row * 64 + (((kh * 4 + l4) ^ (row & 7)) << 3)];
            }
#pragma unroll
            for (int mi = 0; mi < 4; mi++)
#pragma unroll
                for (int nj = 0; nj < 4; nj++)
                    acc[mi][nj] = __builtin_amdgcn_mfma_f32_16x16x32_bf16(a[mi], b[nj], acc[mi][nj], 0, 0, 0);
        }
    }

#pragma unroll
    for (int mi = 0; mi < 4; mi++) {
#pragma unroll
        for (int nj = 0; nj < 4; nj++) {
            int col = n0 + wc * 64 + nj * 16 + l15;
#pragma unroll
            for (int r = 0; r < 4; r++) {
                int row = m0 + wr * 64 + mi * 16 + l4 * 4 + r;
                float v = acc[mi][nj][r];
                if (OUT_F32)
                    ((float*)C)[(size_t)row * Nout + col] = v;
                else
                    ((u16*)C)[(size_t)row * Nout + col] = f2bf(v);
            }
        }
    }
}

// ---------------- causal flash attention: 32x32 MFMA + split-K ----------------
// 256 threads = 4 waves. split mode: grid (8,224), item = by>>3 in 0..27:
//   item<24: qt = 15-(item>>1), seg = item&1 (seg0 = k [0,qt+1) no-diagonal,
//            seg1 = [qt+1, 2qt+2) diagonal); writes UNNORMALIZED partial O
//            (bf16, y-layout) + per-row m,l to ws record.
//   item>=24: qt = 27-item (3..0), full range, writes y directly.
// fallback (split=0): grid (8,128), qt = 15-(by>>3), full range -> y (r16).
// bh = bx*8+(by&7) keeps K/V XCD-local. Longest chain: 32 -> 16 tiles.
__global__ __launch_bounds__(256) void attn(const u16* __restrict__ qkv, u16* __restrict__ y,
                                            u16* __restrict__ part, int split) {
    __shared__ u16 SH[16384];
#define KT(b_) (SH + (b_) * 4096)
#define VT(b_) (SH + 8192 + (b_) * 4096)

    const int t = threadIdx.x;
    const int lane = t & 63;
    const int w = t >> 6;
    const int q31 = lane & 31;
    const int hi = lane >> 5;
    const int bh = blockIdx.x * 8 + (blockIdx.y & 7);
    const int item = blockIdx.y >> 3;
    const int b = bh >> 4, h = bh & 15;

    int qt, kt_lo, kt_hi, rec = 0;
    bool outp = false;
    if (split) {
        if (item < 24) {
            qt = 15 - (item >> 1);
            int seg = item & 1;
            outp = true;
            kt_lo = seg ? (qt + 1) : 0;
            kt_hi = seg ? (2 * qt + 2) : (qt + 1);
            rec = (bh * 12 + (15 - qt)) * 2 + seg;
        } else {
            qt = 27 - item; kt_lo = 0; kt_hi = 2 * qt + 2;
        }
    } else {
        qt = 15 - item; kt_lo = 0; kt_hi = 2 * qt + 2;
    }

    const u16* qbase = qkv + (size_t)(b * Nn) * D3 + h * DHd;
    const u16* Kg = qbase + Dd;
    const u16* Vg = qbase + 2 * Dd;

    const int kr0 = t >> 3;
    const int ks0 = (((t & 7) ^ (kr0 & 7)) << 3);
    const int vi = t & 31;
    const int vsd = (t >> 5) * 8;
    const int vchunk = (2 * vi) >> 3;
    const int vcol = (2 * vi) & 7;

    const int q0 = qt * 128;
    const int qw = q0 + w * 32;

    bf16x8 qf[4];
    {
        const u16* qrow = qbase + (size_t)(qw + q31) * D3 + hi * 8;
        qf[0] = *(const bf16x8*)(qrow);
        qf[1] = *(const bf16x8*)(qrow + 16);
        qf[2] = *(const bf16x8*)(qrow + 32);
        qf[3] = *(const bf16x8*)(qrow + 48);
    }

    f32x16 o0 = {}, o1 = {};
    float m_ = -1e30f, l_ = 0.f;
    u32x4 va, vb_;

    // ---- prologue: stage tile kt_lo into buf 0 ----
    {
        const int k0 = kt_lo * 64;
        GLOAD16(Kg + (size_t)(k0 + kr0) * D3 + ks0, KT(0) + t * 8);
        GLOAD16(Kg + (size_t)(k0 + kr0 + 32) * D3 + ks0, KT(0) + (t + 256) * 8);
        const u16* vr = Vg + (size_t)(k0 + 2 * vi) * D3 + vsd;
        va = *(const u32x4*)vr;
        vb_ = *(const u32x4*)(vr + D3);
    }
    asm volatile("s_waitcnt vmcnt(0)" ::: "memory");
    {
        u16 av[8], bv[8];
        *(u32x4*)av = va; *(u32x4*)bv = vb_;
#pragma unroll
        for (int j = 0; j < 8; j++) {
            int d = vsd + j;
            u32 word = (u32)av[j] | ((u32)bv[j] << 16);
            *(u32*)(VT(0) + d * 64 + ((vchunk ^ (d & 7)) << 3) + vcol) = word;
        }
    }
    __syncthreads();

    int cur = 0;
    for (int kt = kt_lo; kt < kt_hi; ++kt) {
        const int k0 = kt * 64;
        const int havenext = (kt + 1 < kt_hi);

        if (havenext) {
            const int nk0 = k0 + 64;
            GLOAD16(Kg + (size_t)(nk0 + kr0) * D3 + ks0, KT(cur ^ 1) + t * 8);
            GLOAD16(Kg + (size_t)(nk0 + kr0 + 32) * D3 + ks0, KT(cur ^ 1) + (t + 256) * 8);
            const u16* vr = Vg + (size_t)(nk0 + 2 * vi) * D3 + vsd;
            va = *(const u32x4*)vr;
            vb_ = *(const u32x4*)(vr + D3);
        }

        const int dq = qw - k0;     // multiple of 32

        if (dq >= 0) {
            const int two = (dq >= 32);

            // ---- QK^T ----
            f32x16 s0 = {}, s1 = {};
            __builtin_amdgcn_s_setprio(1);
#pragma unroll
            for (int c = 0; c < 4; ++c) {
                bf16x8 kf = *(const bf16x8*)(KT(cur) + q31 * 64 + (((2 * c + hi) ^ (q31 & 7)) << 3));
                s0 = __builtin_amdgcn_mfma_f32_32x32x16_bf16(kf, qf[c], s0, 0, 0, 0);
            }
            if (two) {
#pragma unroll
                for (int c = 0; c < 4; ++c) {
                    bf16x8 kf = *(const bf16x8*)(KT(cur) + (32 + q31) * 64 + (((2 * c + hi) ^ (q31 & 7)) << 3));
                    s1 = __builtin_amdgcn_mfma_f32_32x32x16_bf16(kf, qf[c], s1, 0, 0, 0);
                }
            }
            __builtin_amdgcn_s_setprio(0);

            // ---- causal boundary masks (wave-uniform branches) ----
            if (dq == 0) {
#pragma unroll
                for (int r = 0; r < 16; ++r) {
                    int krel = (r & 3) + 8 * (r >> 2) + 4 * hi;
                    if (krel > q31) s0[r] = -1e30f;
                }
            }
            if (dq == 32) {
#pragma unroll
                for (int r = 0; r < 16; ++r) {
                    int krel = (r & 3) + 8 * (r >> 2) + 4 * hi;
                    if (krel > q31) s1[r] = -1e30f;
                }
            }

            // ---- per-lane max + defer-max fast path ----
            float lm = s0[0];
#pragma unroll
            for (int r = 1; r < 16; ++r) lm = fmaxf(lm, s0[r]);
            if (two) {
#pragma unroll
                for (int r = 0; r < 16; ++r) lm = fmaxf(lm, s1[r]);
            }

            if (!__all(lm <= m_ + 8.f)) {
                float pm = __shfl_xor(lm, 32);
                float vq = fmaxf(lm, pm);
                float newm = fmaxf(m_, vq);
                float corr = fexp2(m_ - newm);
                l_ *= corr;
                o0 = o0 * corr;
                o1 = o1 * corr;
                m_ = newm;
            }

            // ---- exp + pack into bf16 word-pairs ----
            u32 wd0[4][2], wd1[4][2];
#pragma unroll
            for (int g = 0; g < 4; ++g) {
                float p0 = fexp2(s0[4 * g + 0] - m_);
                float p1 = fexp2(s0[4 * g + 1] - m_);
                float p2 = fexp2(s0[4 * g + 2] - m_);
                float p3 = fexp2(s0[4 * g + 3] - m_);
                l_ += (p0 + p1) + (p2 + p3);
                wd0[g][0] = cvtpk_bf16(p0, p1);
                wd0[g][1] = cvtpk_bf16(p2, p3);
            }
            if (two) {
#pragma unroll
                for (int g = 0; g < 4; ++g) {
                    float p0 = fexp2(s1[4 * g + 0] - m_);
                    float p1 = fexp2(s1[4 * g + 1] - m_);
                    float p2 = fexp2(s1[4 * g + 2] - m_);
                    float p3 = fexp2(s1[4 * g + 3] - m_);
                    l_ += (p0 + p1) + (p2 + p3);
                    wd1[g][0] = cvtpk_bf16(p0, p1);
                    wd1[g][1] = cvtpk_bf16(p2, p3);
                }
            }

            // ---- P transpose via permlane32_swap + PV ----
            __builtin_amdgcn_s_setprio(1);
#pragma unroll
            for (int c = 0; c < 2; ++c) {   // k 0..31
                u32 a0 = wd0[2 * c][0], a1 = wd0[2 * c][1];
                u32 b0 = wd0[2 * c + 1][0], b1 = wd0[2 * c + 1][1];
                asm("v_permlane32_swap_b32 %0, %1" : "+v"(a0), "+v"(b0));
                asm("v_permlane32_swap_b32 %0, %1" : "+v"(a1), "+v"(b1));
                union { u32x4 u; bf16x8 f; } pa;
                pa.u[0] = a0; pa.u[1] = a1; pa.u[2] = b0; pa.u[3] = b1;
                bf16x8 v0 = *(const bf16x8*)(VT(cur) + q31 * 64 + (((2 * c + hi) ^ (q31 & 7)) << 3));
                bf16x8 v1 = *(const bf16x8*)(VT(cur) + (32 + q31) * 64 + (((2 * c + hi) ^ (q31 & 7)) << 3));
                o0 = __builtin_amdgcn_mfma_f32_32x32x16_bf16(v0, pa.f, o0, 0, 0, 0);
                o1 = __builtin_amdgcn_mfma_f32_32x32x16_bf16(v1, pa.f, o1, 0, 0, 0);
            }
            if (two) {
#pragma unroll
                for (int c = 0; c < 2; ++c) {   // k 32..63
                    u32 a0 = wd1[2 * c][0], a1 = wd1[2 * c][1];
                    u32 b0 = wd1[2 * c + 1][0], b1 = wd1[2 * c + 1][1];
                    asm("v_permlane32_swap_b32 %0, %1" : "+v"(a0), "+v"(b0));
                    asm("v_permlane32_swap_b32 %0, %1" : "+v"(a1), "+v"(b1));
                    union { u32x4 u; bf16x8 f; } pa;
                    pa.u[0] = a0; pa.u[1] = a1; pa.u[2] = b0; pa.u[3] = b1;
                    int ck = 2 * (c + 2) + hi;
                    bf16x8 v0 = *(const bf16x8*)(VT(cur) + q31 * 64 + ((ck ^ (q31 & 7)) << 3));
                    bf16x8 v1 = *(const bf16x8*)(VT(cur) + (32 + q31) * 64 + ((ck ^ (q31 & 7)) << 3));
                    o0 = __builtin_amdgcn_mfma_f32_32x32x16_bf16(v0, pa.f, o0, 0, 0, 0);
                    o1 = __builtin_amdgcn_mfma_f32_32x32x16_bf16(v1, pa.f, o1, 0, 0, 0);
                }
            }
            __builtin_amdgcn_s_setprio(0);
        }

        // ---- finish staging tile kt+1 ----
        if (havenext) {
            asm volatile("s_waitcnt vmcnt(0)" ::: "memory");
            u16 av[8], bv[8];
            *(u32x4*)av = va; *(u32x4*)bv = vb_;
#pragma unroll
            for (int j = 0; j < 8; j++) {
                int d = vsd + j;
                u32 word = (u32)av[j] | ((u32)bv[j] << 16);
                *(u32*)(VT(cur ^ 1) + d * 64 + ((vchunk ^ (d & 7)) << 3) + vcol) = word;
            }
        }
        __syncthreads();
        cur ^= 1;
    }

    // ---- epilogue ----
    float lq = l_ + __shfl_xor(l_, 32);
    float scl = outp ? 1.f : (1.f / lq);
    u16* Ep = SH + w * 2304;       // 32 rows x 72 u16 per wave
#pragma unroll
    for (int dt = 0; dt < 2; ++dt) {
#pragma unroll
        for (int g = 0; g < 4; ++g) {
#pragma unroll
            for (int s2 = 0; s2 < 2; ++s2) {
                float e0 = (dt ? o1[4 * g + 2 * s2] : o0[4 * g + 2 * s2]) * scl;
                float e1 = (dt ? o1[4 * g + 2 * s2 + 1] : o0[4 * g + 2 * s2 + 1]) * scl;
                u32 word = cvtpk_bf16(e0, e1);
                int chnk = 4 * dt + g;
                *(u32*)(Ep + q31 * 72 + chnk * 8 + 4 * hi + 2 * s2) = word;
            }
        }
    }
    asm volatile("s_waitcnt lgkmcnt(0)" ::: "memory");
    __builtin_amdgcn_sched_barrier(0);
    {
        int qp = lane >> 1;
        int dh = lane & 1;
        u16* dst;
        if (outp) {
            u16* recO = part + (size_t)rec * REC_U16;
            dst = recO + (w * 32 + qp) * 64 + dh * 32;
        } else {
            dst = y + (size_t)(b * Nn + qw + qp) * Dd + h * DHd + dh * 32;
        }
#pragma unroll
        for (int cc = 0; cc < 4; ++cc) {
            int chnk = dh * 4 + cc;
            u32x4 vv = *(const u32x4*)(Ep + qp * 72 + chnk * 8);
            *(u32x4*)(dst + cc * 8) = vv;
        }
    }
    if (outp && hi == 0) {
        u16* recO = part + (size_t)rec * REC_U16;
        float* recM = (float*)(recO + 8192);
        float* recL = recM + 128;
        recM[w * 32 + q31] = m_;
        recL[w * 32 + q31] = lq;
    }
#undef KT
#undef VT
}

// ---------------- split-K merge: combine 2 segment partials -> y ----------------
__global__ __launch_bounds__(256) void attn_merge(const u16* __restrict__ part,
                                                  u16* __restrict__ y) {
    const int p = blockIdx.x;            // 0..767: bh*12 + (15-qt)
    const int bh = p / 12;
    const int j = p - bh * 12;
    const int qt = 15 - j;
    const int b = bh >> 4, h = bh & 15;

    const u16* rA = part + (size_t)(p * 2) * REC_U16;
    const u16* rB = rA + REC_U16;
    const float* mA = (const float*)(rA + 8192);
    const float* lA = mA + 128;
    const float* mB = (const float*)(rB + 8192);
    const float* lB = mB + 128;

    const int t = threadIdx.x;
    const int row = t >> 1;
    const int half = t & 1;

    float ma = mA[row], mb = mB[row];
    float la = lA[row], lb = lB[row];
    float M = fmaxf(ma, mb);
    float wa = fexp2(ma - M), wb = fexp2(mb - M);
    float inv = 1.f / (la * wa + lb * wb);
    wa *= inv; wb *= inv;

    const u16* oa = rA + row * 64 + half * 32;
    const u16* ob = rB + row * 64 + half * 32;
    u16* yr = y + (size_t)(b * Nn + qt * 128 + row) * Dd + h * DHd + half * 32;

#pragma unroll
    for (int g = 0; g < 4; ++g) {
        u32x4 ua = *(const u32x4*)(oa + g * 8);
        u32x4 ub = *(const u32x4*)(ob + g * 8);
        u16 av[8], bv[8];
        *(u32x4*)av = ua; *(u32x4*)bv = ub;
        u32 outw[4];
#pragma unroll
        for (int k = 0; k < 4; ++k) {
            float v0 = bf2f(av[2 * k]) * wa + bf2f(bv[2 * k]) * wb;
            float v1 = bf2f(av[2 * k + 1]) * wa + bf2f(bv[2 * k + 1]) * wb;
            outw[k] = cvtpk_bf16(v0, v1);
        }
        *(u32x4*)(yr + g * 8) = *(u32x4*)outw;
    }
}

extern "C" void kernel_launch(void* const* d_in, const int* in_sizes, int n_in,
                              void* d_out, int out_size, void* d_ws, size_t ws_size,
                              hipStream_t stream) {
    const float* x = (const float*)d_in[0];
    const float* Wqkv = (const float*)d_in[1];
    const float* Wout = (const float*)d_in[2];

    char* ws = (char*)d_ws;
    size_t off = 0;
    u16* xb = (u16*)(ws + off);    off += (size_t)Mm * Dd * 2;
    u16* wqkvb = (u16*)(ws + off); off += (size_t)D3 * Dd * 2;
    u16* woutb = (u16*)(ws + off); off += (size_t)Dd * Dd * 2;
    u16* qkv = (u16*)(ws + off);   off += (size_t)Mm * D3 * 2;
    u16* yb = (u16*)(ws + off);    off += (size_t)Mm * Dd * 2;
    u16* part = (u16*)(ws + off);  // +26.7 MB when split

    const int split = (ws_size >= WS_NEED) ? 1 : 0;

    const float SCL = 0.125f * 1.4426950408889634f;  // (1/sqrt(DH)) * log2(e)

    cvt_all<<<4096, 256, 0, stream>>>(x, Wqkv, Wout, xb, wqkvb, woutb, SCL);

    gemm_bt<0><<<dim3(D3 / 128, Mm / 128), 256, 0, stream>>>(xb, wqkvb, qkv, Mm, D3, Dd);
    attn<<<dim3(8, split ? 224 : 128), 256, 0, stream>>>(qkv, yb, part, split);
    if (split)
        attn_merge<<<768, 256, 0, stream>>>(part, yb);
    gemm_bt<1><<<dim3(Dd / 128, Mm / 128), 256, 0, stream>>>(yb, woutb, d_out, Mm, Dd, Dd);
}

// Round 18
// 161.271 us; speedup vs baseline: 1.0802x; 1.0802x over previous
//
#include <hip/hip_runtime.h>
#include <hip/hip_bf16.h>
#include <stdint.h>

#define Bb 4
#define Nn 2048
#define Dd 1024
#define Hh 16
#define DHd 64
#define Mm (Bb*Nn)     /* 8192 */
#define D3 (3*Dd)      /* 3072 */

typedef unsigned short u16;
typedef unsigned int u32;
typedef __attribute__((ext_vector_type(8))) short bf16x8;
typedef __attribute__((ext_vector_type(4))) float f32x4;
typedef __attribute__((ext_vector_type(16))) float f32x16;
typedef __attribute__((ext_vector_type(4))) unsigned int u32x4;

__device__ __forceinline__ u16 f2bf(float f) {
    unsigned int u = __float_as_uint(f);
    u = (u + 0x7FFFu + ((u >> 16) & 1u)) >> 16;
    return (u16)u;
}

__device__ __forceinline__ u32 cvtpk_bf16(float lo, float hi) {
    u32 r;
    asm("v_cvt_pk_bf16_f32 %0, %1, %2" : "=v"(r) : "v"(lo), "v"(hi));
    return r;
}

// bare HW exp2 — no libm guards (inputs bounded by defer-max; -huge underflows to 0)
__device__ __forceinline__ float fexp2(float x) {
    float r;
    asm("v_exp_f32 %0, %1" : "=v"(r) : "v"(x));
    return r;
}

#define F3(a, b, c) fmaxf(fmaxf((a), (b)), (c))

#define GLOAD16(g, l)                                                          \
    __builtin_amdgcn_global_load_lds(                                          \
        (const __attribute__((address_space(1))) unsigned int*)(g),            \
        (__attribute__((address_space(3))) unsigned int*)(l), 16, 0, 0)

// ---------------- fused fp32 -> bf16 convert for all three inputs ----------
__global__ void cvt_all(const float* __restrict__ x, const float* __restrict__ wqkv,
                        const float* __restrict__ wout, u16* __restrict__ xb,
                        u16* __restrict__ wqkvb, u16* __restrict__ woutb, float s) {
    const int A4 = Mm * Dd / 4;
    const int B4 = D3 * Dd / 4;
    const int C4 = Dd * Dd / 4;
    const int QCUT = Dd * Dd / 4;
    const int total = A4 + B4 + C4;
    int i = blockIdx.x * blockDim.x + threadIdx.x;
    const int stride = gridDim.x * blockDim.x;
    for (; i < total; i += stride) {
        const float* src; u16* dst; int j; float sc = 1.f;
        if (i < A4) { src = x; dst = xb; j = i; }
        else if (i < A4 + B4) { j = i - A4; src = wqkv; dst = wqkvb; if (j < QCUT) sc = s; }
        else { j = i - A4 - B4; src = wout; dst = woutb; }
        float4 v = ((const float4*)src)[j];
        u16 o0 = f2bf(v.x * sc), o1 = f2bf(v.y * sc), o2 = f2bf(v.z * sc), o3 = f2bf(v.w * sc);
        ((uint2*)dst)[j] = make_uint2((u32)o0 | ((u32)o1 << 16), (u32)o2 | ((u32)o3 << 16));
    }
}

// ---------------- bf16 GEMM: C[M][N] = A[M][K] * B[N][K]^T ----------------
// 128x128 tile, BK=64, T2 LDS swizzle, T1 XCD swizzle (r13, proven).
template<int OUT_F32>
__global__ __launch_bounds__(256) void gemm_bt(const u16* __restrict__ A,
                                               const u16* __restrict__ Bm,
                                               void* __restrict__ C,
                                               int M, int Nout, int K) {
    __shared__ u16 As[128 * 64];
    __shared__ u16 Bs[128 * 64];
    const int t = threadIdx.x;
    const int lane = t & 63;
    const int w = t >> 6;
    const int wr = w >> 1, wc = w & 1;
    const int l15 = lane & 15, l4 = lane >> 4;

    const int gx = gridDim.x;
    const int linear = blockIdx.y * gx + blockIdx.x;
    const int cpx = (gx * gridDim.y) >> 3;
    const int tile = (linear & 7) * cpx + (linear >> 3);
    const int m0 = (tile / gx) * 128;
    const int n0 = (tile % gx) * 128;

    f32x4 acc[4][4] = {};

    for (int k0 = 0; k0 < K; k0 += 64) {
        __syncthreads();
#pragma unroll
        for (int i = 0; i < 4; i++) {
            int chunk = i * 256 + t;
            int row = chunk >> 3;
            int csw = ((chunk & 7) ^ (row & 7)) << 3;
            GLOAD16(A + (size_t)(m0 + row) * K + k0 + csw, &As[chunk * 8]);
            GLOAD16(Bm + (size_t)(n0 + row) * K + k0 + csw, &Bs[chunk * 8]);
        }
        __syncthreads();

#pragma unroll
        for (int kh = 0; kh < 2; kh++) {
            bf16x8 a[4], b[4];
#pragma unroll
            for (int mi = 0; mi < 4; mi++) {
                int row = wr * 64 + mi * 16 + l15;
                a[mi] = *(const bf16x8*)&As[row * 64 + (((kh * 4 + l4) ^ (row & 7)) << 3)];
            }
#pragma unroll
            for (int nj = 0; nj < 4; nj++) {
                int row = wc * 64 + nj * 16 + l15;
                b[nj] = *(const bf16x8*)&Bs[row * 64 + (((kh * 4 + l4) ^ (row & 7)) << 3)];
            }
#pragma unroll
            for (int mi = 0; mi < 4; mi++)
#pragma unroll
                for (int nj = 0; nj < 4; nj++)
                    acc[mi][nj] = __builtin_amdgcn_mfma_f32_16x16x32_bf16(a[mi], b[nj], acc[mi][nj], 0, 0, 0);
        }
    }

#pragma unroll
    for (int mi = 0; mi < 4; mi++) {
#pragma unroll
        for (int nj = 0; nj < 4; nj++) {
            int col = n0 + wc * 64 + nj * 16 + l15;
#pragma unroll
            for (int r = 0; r < 4; r++) {
                int row = m0 + wr * 64 + mi * 16 + l4 * 4 + r;
                float v = acc[mi][nj][r];
                if (OUT_F32)
                    ((float*)C)[(size_t)row * Nout + col] = v;
                else
                    ((u16*)C)[(size_t)row * Nout + col] = f2bf(v);
            }
        }
    }
}

// ---------------- causal flash attention: 32x32 MFMA structure ----------------
// grid (8, 128), 256 threads = 4 waves, ONE 128-row q-tile per block
// (qt = 15 - by>>3, long-first). bh = bx*8+(by&7) keeps K/V XCD-local.
// Wave w owns q-rows [q0+32w, +32); lane q = lane&31, hi = lane>>5.
// Swapped QK^T via mfma_32x32x16 (S^T[k][q]), per-lane softmax,
// P->B-frag via v_permlane32_swap_b32, O^T accum f32x16.
// VALU cuts (r18): softmax denominator via ones-A MFMA into lacc (replaces
// 24 v_add/tile + epilogue shfl); V staging pack via v_perm_b32 (1 inst per
// packed word); per-lane max via max3 trees. KVBLK=64 double-buffered.
__global__ __launch_bounds__(256) void attn(const u16* __restrict__ qkv, u16* __restrict__ y) {
    __shared__ u16 SH[16384];          // 32 KB pool: Kt buf0/1, Vt buf0/1; epilogue reuse
#define KT(b_) (SH + (b_) * 4096)
#define VT(b_) (SH + 8192 + (b_) * 4096)

    const int t = threadIdx.x;          // 0..255
    const int lane = t & 63;
    const int w = t >> 6;               // 0..3
    const int q31 = lane & 31;
    const int hi = lane >> 5;
    const int bh = blockIdx.x * 8 + (blockIdx.y & 7);
    const int qt = 15 - (int)(blockIdx.y >> 3);     // long blocks dispatched first
    const int b = bh >> 4, h = bh & 15;

    const u16* qbase = qkv + (size_t)(b * Nn) * D3 + h * DHd;
    const u16* Kg = qbase + Dd;
    const u16* Vg = qbase + 2 * Dd;

    // K staging: thread stages chunks t (row 0..31) and t+256 (row 32..63)
    const int kr0 = t >> 3;
    const int ks0 = (((t & 7) ^ (kr0 & 7)) << 3);
    // V staging: rows (2vi, 2vi+1), dims vsd..vsd+7
    const int vi = t & 31;
    const int vsd = (t >> 5) * 8;
    const int vchunk = (2 * vi) >> 3;
    const int vcol = (2 * vi) & 7;

    union { u32x4 u; bf16x8 f; } one_;
    one_.u[0] = one_.u[1] = one_.u[2] = one_.u[3] = 0x3F803F80u;   // bf16 1.0 x8

    const int q0 = qt * 128;
    const int ktmax = 2 * qt + 1;
    const int qw = q0 + w * 32;

    // Q fragments (B-operand): lane holds Q[d = c*16 + hi*8 + j][q = qw+q31]
    bf16x8 qf[4];
    {
        const u16* qrow = qbase + (size_t)(qw + q31) * D3 + hi * 8;
        qf[0] = *(const bf16x8*)(qrow);
        qf[1] = *(const bf16x8*)(qrow + 16);
        qf[2] = *(const bf16x8*)(qrow + 32);
        qf[3] = *(const bf16x8*)(qrow + 48);
    }

    f32x16 o0 = {}, o1 = {};
    f32x16 lacc = {};                    // lacc[0] = softmax denominator (ones-MFMA)
    float m_ = -1e30f;
    u32x4 va, vb_;

    // ---- prologue: stage tile 0 into buf 0 ----
    GLOAD16(Kg + (size_t)kr0 * D3 + ks0, KT(0) + t * 8);
    GLOAD16(Kg + (size_t)(kr0 + 32) * D3 + ks0, KT(0) + (t + 256) * 8);
    {
        const u16* vr = Vg + (size_t)(2 * vi) * D3 + vsd;
        va = *(const u32x4*)vr;
        vb_ = *(const u32x4*)(vr + D3);
    }
    asm volatile("s_waitcnt vmcnt(0)" ::: "memory");
#pragma unroll
    for (int k = 0; k < 4; k++) {
        int d0 = vsd + 2 * k;
        u32 wlo = __builtin_amdgcn_perm(vb_[k], va[k], 0x05040100u);   // (A.lo, B.lo)
        u32 whi = __builtin_amdgcn_perm(vb_[k], va[k], 0x07060302u);   // (A.hi, B.hi)
        *(u32*)(VT(0) + d0 * 64 + ((vchunk ^ (d0 & 7)) << 3) + vcol) = wlo;
        *(u32*)(VT(0) + (d0 + 1) * 64 + ((vchunk ^ ((d0 + 1) & 7)) << 3) + vcol) = whi;
    }
    __syncthreads();

    int cur = 0;
    for (int kt = 0; kt <= ktmax; ++kt) {
        const int k0 = kt * 64;
        const int havenext = (kt < ktmax);

        if (havenext) {
            const int nk0 = k0 + 64;
            GLOAD16(Kg + (size_t)(nk0 + kr0) * D3 + ks0, KT(cur ^ 1) + t * 8);
            GLOAD16(Kg + (size_t)(nk0 + kr0 + 32) * D3 + ks0, KT(cur ^ 1) + (t + 256) * 8);
            const u16* vr = Vg + (size_t)(nk0 + 2 * vi) * D3 + vsd;
            va = *(const u32x4*)vr;
            vb_ = *(const u32x4*)(vr + D3);
        }

        const int dq = qw - k0;     // multiple of 32

        if (dq >= 0) {
            const int two = (dq >= 32);

            // ---- QK^T ----
            f32x16 s0 = {}, s1 = {};
            __builtin_amdgcn_s_setprio(1);
#pragma unroll
            for (int c = 0; c < 4; ++c) {
                bf16x8 kf = *(const bf16x8*)(KT(cur) + q31 * 64 + (((2 * c + hi) ^ (q31 & 7)) << 3));
                s0 = __builtin_amdgcn_mfma_f32_32x32x16_bf16(kf, qf[c], s0, 0, 0, 0);
            }
            if (two) {
#pragma unroll
                for (int c = 0; c < 4; ++c) {
                    bf16x8 kf = *(const bf16x8*)(KT(cur) + (32 + q31) * 64 + (((2 * c + hi) ^ (q31 & 7)) << 3));
                    s1 = __builtin_amdgcn_mfma_f32_32x32x16_bf16(kf, qf[c], s1, 0, 0, 0);
                }
            }
            __builtin_amdgcn_s_setprio(0);

            // ---- causal boundary masks (wave-uniform branches) ----
            if (dq == 0) {
#pragma unroll
                for (int r = 0; r < 16; ++r) {
                    int krel = (r & 3) + 8 * (r >> 2) + 4 * hi;
                    if (krel > q31) s0[r] = -1e30f;
                }
            }
            if (dq == 32) {
#pragma unroll
                for (int r = 0; r < 16; ++r) {
                    int krel = (r & 3) + 8 * (r >> 2) + 4 * hi;
                    if (krel > q31) s1[r] = -1e30f;
                }
            }

            // ---- per-lane max (max3 trees) + defer-max fast path ----
            float a0 = F3(s0[0], s0[1], s0[2]);
            float a1 = F3(s0[3], s0[4], s0[5]);
            float a2 = F3(s0[6], s0[7], s0[8]);
            float a3 = F3(s0[9], s0[10], s0[11]);
            float a4 = F3(s0[12], s0[13], s0[14]);
            float lm = F3(F3(a0, a1, a2), a3, F3(a4, s0[15], -3.0e38f));
            if (two) {
                float b0 = F3(s1[0], s1[1], s1[2]);
                float b1 = F3(s1[3], s1[4], s1[5]);
                float b2 = F3(s1[6], s1[7], s1[8]);
                float b3 = F3(s1[9], s1[10], s1[11]);
                float b4 = F3(s1[12], s1[13], s1[14]);
                lm = fmaxf(lm, F3(F3(b0, b1, b2), b3, F3(b4, s1[15], -3.0e38f)));
            }

            if (!__all(lm <= m_ + 8.f)) {
                float pm = __shfl_xor(lm, 32);
                float vq = fmaxf(lm, pm);
                float newm = fmaxf(m_, vq);
                float corr = fexp2(m_ - newm);
                lacc[0] *= corr;
                o0 = o0 * corr;
                o1 = o1 * corr;
                m_ = newm;
            }

            // ---- exp + pack into bf16 word-pairs ----
            u32 wd0[4][2], wd1[4][2];
#pragma unroll
            for (int g = 0; g < 4; ++g) {
                float p0 = fexp2(s0[4 * g + 0] - m_);
                float p1 = fexp2(s0[4 * g + 1] - m_);
                float p2 = fexp2(s0[4 * g + 2] - m_);
                float p3 = fexp2(s0[4 * g + 3] - m_);
                wd0[g][0] = cvtpk_bf16(p0, p1);
                wd0[g][1] = cvtpk_bf16(p2, p3);
            }
            if (two) {
#pragma unroll
                for (int g = 0; g < 4; ++g) {
                    float p0 = fexp2(s1[4 * g + 0] - m_);
                    float p1 = fexp2(s1[4 * g + 1] - m_);
                    float p2 = fexp2(s1[4 * g + 2] - m_);
                    float p3 = fexp2(s1[4 * g + 3] - m_);
                    wd1[g][0] = cvtpk_bf16(p0, p1);
                    wd1[g][1] = cvtpk_bf16(p2, p3);
                }
            }

            // ---- P transpose via permlane32_swap + PV (+ ones-MFMA for l) ----
            __builtin_amdgcn_s_setprio(1);
#pragma unroll
            for (int c = 0; c < 2; ++c) {   // k 0..31
                u32 a0w = wd0[2 * c][0], a1w = wd0[2 * c][1];
                u32 b0w = wd0[2 * c + 1][0], b1w = wd0[2 * c + 1][1];
                asm("v_permlane32_swap_b32 %0, %1" : "+v"(a0w), "+v"(b0w));
                asm("v_permlane32_swap_b32 %0, %1" : "+v"(a1w), "+v"(b1w));
                union { u32x4 u; bf16x8 f; } pa;
                pa.u[0] = a0w; pa.u[1] = a1w; pa.u[2] = b0w; pa.u[3] = b1w;
                bf16x8 v0 = *(const bf16x8*)(VT(cur) + q31 * 64 + (((2 * c + hi) ^ (q31 & 7)) << 3));
                bf16x8 v1 = *(const bf16x8*)(VT(cur) + (32 + q31) * 64 + (((2 * c + hi) ^ (q31 & 7)) << 3));
                o0 = __builtin_amdgcn_mfma_f32_32x32x16_bf16(v0, pa.f, o0, 0, 0, 0);
                o1 = __builtin_amdgcn_mfma_f32_32x32x16_bf16(v1, pa.f, o1, 0, 0, 0);
                lacc = __builtin_amdgcn_mfma_f32_32x32x16_bf16(one_.f, pa.f, lacc, 0, 0, 0);
            }
            if (two) {
#pragma unroll
                for (int c = 0; c < 2; ++c) {   // k 32..63
                    u32 a0w = wd1[2 * c][0], a1w = wd1[2 * c][1];
                    u32 b0w = wd1[2 * c + 1][0], b1w = wd1[2 * c + 1][1];
                    asm("v_permlane32_swap_b32 %0, %1" : "+v"(a0w), "+v"(b0w));
                    asm("v_permlane32_swap_b32 %0, %1" : "+v"(a1w), "+v"(b1w));
                    union { u32x4 u; bf16x8 f; } pa;
                    pa.u[0] = a0w; pa.u[1] = a1w; pa.u[2] = b0w; pa.u[3] = b1w;
                    int ck = 2 * (c + 2) + hi;
                    bf16x8 v0 = *(const bf16x8*)(VT(cur) + q31 * 64 + ((ck ^ (q31 & 7)) << 3));
                    bf16x8 v1 = *(const bf16x8*)(VT(cur) + (32 + q31) * 64 + ((ck ^ (q31 & 7)) << 3));
                    o0 = __builtin_amdgcn_mfma_f32_32x32x16_bf16(v0, pa.f, o0, 0, 0, 0);
                    o1 = __builtin_amdgcn_mfma_f32_32x32x16_bf16(v1, pa.f, o1, 0, 0, 0);
                    lacc = __builtin_amdgcn_mfma_f32_32x32x16_bf16(one_.f, pa.f, lacc, 0, 0, 0);
                }
            }
            __builtin_amdgcn_s_setprio(0);
        }

        // ---- finish staging tile kt+1 ----
        if (havenext) {
            asm volatile("s_waitcnt vmcnt(0)" ::: "memory");
#pragma unroll
            for (int k = 0; k < 4; k++) {
                int d0 = vsd + 2 * k;
                u32 wlo = __builtin_amdgcn_perm(vb_[k], va[k], 0x05040100u);
                u32 whi = __builtin_amdgcn_perm(vb_[k], va[k], 0x07060302u);
                *(u32*)(VT(cur ^ 1) + d0 * 64 + ((vchunk ^ (d0 & 7)) << 3) + vcol) = wlo;
                *(u32*)(VT(cur ^ 1) + (d0 + 1) * 64 + ((vchunk ^ ((d0 + 1) & 7)) << 3) + vcol) = whi;
            }
        }
        __syncthreads();
        cur ^= 1;
    }

    // ---- epilogue: normalize, transpose O via LDS (72-u16 rows), store y ----
    float linv = 1.f / lacc[0];
    u16* Ep = SH + w * 2304;       // 32 rows x 72 u16 per wave
#pragma unroll
    for (int dt = 0; dt < 2; ++dt) {
#pragma unroll
        for (int g = 0; g < 4; ++g) {
#pragma unroll
            for (int s2 = 0; s2 < 2; ++s2) {
                float e0 = (dt ? o1[4 * g + 2 * s2] : o0[4 * g + 2 * s2]) * linv;
                float e1 = (dt ? o1[4 * g + 2 * s2 + 1] : o0[4 * g + 2 * s2 + 1]) * linv;
                u32 word = cvtpk_bf16(e0, e1);
                int chnk = 4 * dt + g;
                *(u32*)(Ep + q31 * 72 + chnk * 8 + 4 * hi + 2 * s2) = word;
            }
        }
    }
    asm volatile("s_waitcnt lgkmcnt(0)" ::: "memory");
    __builtin_amdgcn_sched_barrier(0);
    {
        int qp = lane >> 1;
        int dh = lane & 1;
        u16* yrow = y + (size_t)(b * Nn + qw + qp) * Dd + h * DHd + dh * 32;
#pragma unroll
        for (int cc = 0; cc < 4; ++cc) {
            int chnk = dh * 4 + cc;
            u32x4 vv = *(const u32x4*)(Ep + qp * 72 + chnk * 8);
            *(u32x4*)(yrow + cc * 8) = vv;
        }
    }
#undef KT
#undef VT
}

extern "C" void kernel_launch(void* const* d_in, const int* in_sizes, int n_in,
                              void* d_out, int out_size, void* d_ws, size_t ws_size,
                              hipStream_t stream) {
    const float* x = (const float*)d_in[0];
    const float* Wqkv = (const float*)d_in[1];
    const float* Wout = (const float*)d_in[2];

    char* ws = (char*)d_ws;
    size_t off = 0;
    u16* xb = (u16*)(ws + off);    off += (size_t)Mm * Dd * 2;
    u16* wqkvb = (u16*)(ws + off); off += (size_t)D3 * Dd * 2;
    u16* woutb = (u16*)(ws + off); off += (size_t)Dd * Dd * 2;
    u16* qkv = (u16*)(ws + off);   off += (size_t)Mm * D3 * 2;
    u16* yb = (u16*)(ws + off);    off += (size_t)Mm * Dd * 2;

    const float SCL = 0.125f * 1.4426950408889634f;  // (1/sqrt(DH)) * log2(e)

    cvt_all<<<4096, 256, 0, stream>>>(x, Wqkv, Wout, xb, wqkvb, woutb, SCL);

    gemm_bt<0><<<dim3(D3 / 128, Mm / 128), 256, 0, stream>>>(xb, wqkvb, qkv, Mm, D3, Dd);
    attn<<<dim3(8, 128), 256, 0, stream>>>(qkv, yb);
    gemm_bt<1><<<dim3(Dd / 128, Mm / 128), 256, 0, stream>>>(yb, woutb, d_out, Mm, Dd, Dd);
}

// Round 19
// 153.487 us; speedup vs baseline: 1.1349x; 1.0507x over previous
//
#include <hip/hip_runtime.h>
#include <hip/hip_bf16.h>
#include <stdint.h>

#define Bb 4
#define Nn 2048
#define Dd 1024
#define Hh 16
#define DHd 64
#define Mm (Bb*Nn)     /* 8192 */
#define D3 (3*Dd)      /* 3072 */

typedef unsigned short u16;
typedef unsigned int u32;
typedef __attribute__((ext_vector_type(8))) short bf16x8;
typedef __attribute__((ext_vector_type(4))) float f32x4;
typedef __attribute__((ext_vector_type(16))) float f32x16;
typedef __attribute__((ext_vector_type(2))) unsigned int u32x2;
typedef __attribute__((ext_vector_type(4))) unsigned int u32x4;

__device__ __forceinline__ u16 f2bf(float f) {
    unsigned int u = __float_as_uint(f);
    u = (u + 0x7FFFu + ((u >> 16) & 1u)) >> 16;
    return (u16)u;
}

__device__ __forceinline__ u32 cvtpk_bf16(float lo, float hi) {
    u32 r;
    asm("v_cvt_pk_bf16_f32 %0, %1, %2" : "=v"(r) : "v"(lo), "v"(hi));
    return r;
}

// bare HW exp2 — no libm guards (inputs bounded by defer-max; -huge underflows to 0)
__device__ __forceinline__ float fexp2(float x) {
    float r;
    asm("v_exp_f32 %0, %1" : "=v"(r) : "v"(x));
    return r;
}

#define F3(a, b, c) fmaxf(fmaxf((a), (b)), (c))

#define GLOAD16(g, l)                                                          \
    __builtin_amdgcn_global_load_lds(                                          \
        (const __attribute__((address_space(1))) unsigned int*)(g),            \
        (__attribute__((address_space(3))) unsigned int*)(l), 16, 0, 0)

// ---------------- fused fp32 -> bf16 convert for all three inputs ----------
__global__ void cvt_all(const float* __restrict__ x, const float* __restrict__ wqkv,
                        const float* __restrict__ wout, u16* __restrict__ xb,
                        u16* __restrict__ wqkvb, u16* __restrict__ woutb, float s) {
    const int A4 = Mm * Dd / 4;
    const int B4 = D3 * Dd / 4;
    const int C4 = Dd * Dd / 4;
    const int QCUT = Dd * Dd / 4;
    const int total = A4 + B4 + C4;
    int i = blockIdx.x * blockDim.x + threadIdx.x;
    const int stride = gridDim.x * blockDim.x;
    for (; i < total; i += stride) {
        const float* src; u16* dst; int j; float sc = 1.f;
        if (i < A4) { src = x; dst = xb; j = i; }
        else if (i < A4 + B4) { j = i - A4; src = wqkv; dst = wqkvb; if (j < QCUT) sc = s; }
        else { j = i - A4 - B4; src = wout; dst = woutb; }
        float4 v = ((const float4*)src)[j];
        u16 o0 = f2bf(v.x * sc), o1 = f2bf(v.y * sc), o2 = f2bf(v.z * sc), o3 = f2bf(v.w * sc);
        ((uint2*)dst)[j] = make_uint2((u32)o0 | ((u32)o1 << 16), (u32)o2 | ((u32)o3 << 16));
    }
}

// ---------------- bf16 GEMM: C[M][N] = A[M][K] * B[N][K]^T ----------------
// 128x128 tile, BK=64, T2 LDS swizzle, T1 XCD swizzle (r13, proven).
template<int OUT_F32>
__global__ __launch_bounds__(256) void gemm_bt(const u16* __restrict__ A,
                                               const u16* __restrict__ Bm,
                                               void* __restrict__ C,
                                               int M, int Nout, int K) {
    __shared__ u16 As[128 * 64];
    __shared__ u16 Bs[128 * 64];
    const int t = threadIdx.x;
    const int lane = t & 63;
    const int w = t >> 6;
    const int wr = w >> 1, wc = w & 1;
    const int l15 = lane & 15, l4 = lane >> 4;

    const int gx = gridDim.x;
    const int linear = blockIdx.y * gx + blockIdx.x;
    const int cpx = (gx * gridDim.y) >> 3;
    const int tile = (linear & 7) * cpx + (linear >> 3);
    const int m0 = (tile / gx) * 128;
    const int n0 = (tile % gx) * 128;

    f32x4 acc[4][4] = {};

    for (int k0 = 0; k0 < K; k0 += 64) {
        __syncthreads();
#pragma unroll
        for (int i = 0; i < 4; i++) {
            int chunk = i * 256 + t;
            int row = chunk >> 3;
            int csw = ((chunk & 7) ^ (row & 7)) << 3;
            GLOAD16(A + (size_t)(m0 + row) * K + k0 + csw, &As[chunk * 8]);
            GLOAD16(Bm + (size_t)(n0 + row) * K + k0 + csw, &Bs[chunk * 8]);
        }
        __syncthreads();

#pragma unroll
        for (int kh = 0; kh < 2; kh++) {
            bf16x8 a[4], b[4];
#pragma unroll
            for (int mi = 0; mi < 4; mi++) {
                int row = wr * 64 + mi * 16 + l15;
                a[mi] = *(const bf16x8*)&As[row * 64 + (((kh * 4 + l4) ^ (row & 7)) << 3)];
            }
#pragma unroll
            for (int nj = 0; nj < 4; nj++) {
                int row = wc * 64 + nj * 16 + l15;
                b[nj] = *(const bf16x8*)&Bs[row * 64 + (((kh * 4 + l4) ^ (row & 7)) << 3)];
            }
#pragma unroll
            for (int mi = 0; mi < 4; mi++)
#pragma unroll
                for (int nj = 0; nj < 4; nj++)
                    acc[mi][nj] = __builtin_amdgcn_mfma_f32_16x16x32_bf16(a[mi], b[nj], acc[mi][nj], 0, 0, 0);
        }
    }

#pragma unroll
    for (int mi = 0; mi < 4; mi++) {
#pragma unroll
        for (int nj = 0; nj < 4; nj++) {
            int col = n0 + wc * 64 + nj * 16 + l15;
#pragma unroll
            for (int r = 0; r < 4; r++) {
                int row = m0 + wr * 64 + mi * 16 + l4 * 4 + r;
                float v = acc[mi][nj][r];
                if (OUT_F32)
                    ((float*)C)[(size_t)row * Nout + col] = v;
                else
                    ((u16*)C)[(size_t)row * Nout + col] = f2bf(v);
            }
        }
    }
}

// ---------------- causal flash attention: 32x32 MFMA, 256-row q-tile ----------------
// grid (8, 64), 512 threads = 8 waves, ONE 256-row q-tile per block
// (qt = 7 - by>>3, long-first). Each staged 64x64 K/V tile feeds 8 waves
// (2x the r18 arithmetic intensity per stage). bh = bx*8+(by&7) keeps K/V
// XCD-local. Wave w owns q-rows [q0+32w, +32); lane q = lane&31, hi = lane>>5.
// Inner loop identical to r18 (proven): swapped QK^T via mfma_32x32x16,
// per-lane softmax (max3 trees, defer-max), P->B-frag via permlane32_swap,
// softmax denominator via ones-A MFMA (lacc), V pack via v_perm_b32,
// O^T accum f32x16, epilogue O-transpose via LDS. KVBLK=64 double-buffered.
__global__ __launch_bounds__(512) void attn(const u16* __restrict__ qkv, u16* __restrict__ y) {
    __shared__ u16 SH[16384];          // 32 KB pool: Kt buf0/1, Vt buf0/1; epilogue reuse
#define KT(b_) (SH + (b_) * 4096)
#define VT(b_) (SH + 8192 + (b_) * 4096)

    const int t = threadIdx.x;          // 0..511
    const int lane = t & 63;
    const int w = t >> 6;               // 0..7
    const int q31 = lane & 31;
    const int hi = lane >> 5;
    const int bh = blockIdx.x * 8 + (blockIdx.y & 7);
    const int qt = 7 - (int)(blockIdx.y >> 3);      // long blocks dispatched first
    const int b = bh >> 4, h = bh & 15;

    const u16* qbase = qkv + (size_t)(b * Nn) * D3 + h * DHd;
    const u16* Kg = qbase + Dd;
    const u16* Vg = qbase + 2 * Dd;

    // K staging: thread stages chunk t (512 chunks of 16B = 64 rows x 8)
    const int kr0 = t >> 3;
    const int ks0 = (((t & 7) ^ (kr0 & 7)) << 3);
    // V staging: rows (2vi, 2vi+1), dims vsd..vsd+3
    const int vi = t & 31;
    const int vsd = (t >> 5) * 4;
    const int vchunk = (2 * vi) >> 3;
    const int vcol = (2 * vi) & 7;

    union { u32x4 u; bf16x8 f; } one_;
    one_.u[0] = one_.u[1] = one_.u[2] = one_.u[3] = 0x3F803F80u;   // bf16 1.0 x8

    const int q0 = qt * 256;
    const int ktmax = 4 * qt + 3;
    const int qw = q0 + w * 32;

    // Q fragments (B-operand): lane holds Q[d = c*16 + hi*8 + j][q = qw+q31]
    bf16x8 qf[4];
    {
        const u16* qrow = qbase + (size_t)(qw + q31) * D3 + hi * 8;
        qf[0] = *(const bf16x8*)(qrow);
        qf[1] = *(const bf16x8*)(qrow + 16);
        qf[2] = *(const bf16x8*)(qrow + 32);
        qf[3] = *(const bf16x8*)(qrow + 48);
    }

    f32x16 o0 = {}, o1 = {};
    f32x16 lacc = {};                    // lacc[0] = softmax denominator (ones-MFMA)
    float m_ = -1e30f;
    u32x2 va, vb_;

    // ---- prologue: stage tile 0 into buf 0 ----
    GLOAD16(Kg + (size_t)kr0 * D3 + ks0, KT(0) + t * 8);
    {
        const u16* vr = Vg + (size_t)(2 * vi) * D3 + vsd;
        va = *(const u32x2*)vr;
        vb_ = *(const u32x2*)(vr + D3);
    }
    asm volatile("s_waitcnt vmcnt(0)" ::: "memory");
#pragma unroll
    for (int k = 0; k < 2; k++) {
        int d0 = vsd + 2 * k;
        u32 wlo = __builtin_amdgcn_perm(vb_[k], va[k], 0x05040100u);   // (A.lo, B.lo)
        u32 whi = __builtin_amdgcn_perm(vb_[k], va[k], 0x07060302u);   // (A.hi, B.hi)
        *(u32*)(VT(0) + d0 * 64 + ((vchunk ^ (d0 & 7)) << 3) + vcol) = wlo;
        *(u32*)(VT(0) + (d0 + 1) * 64 + ((vchunk ^ ((d0 + 1) & 7)) << 3) + vcol) = whi;
    }
    __syncthreads();

    int cur = 0;
    for (int kt = 0; kt <= ktmax; ++kt) {
        const int k0 = kt * 64;
        const int havenext = (kt < ktmax);

        if (havenext) {
            const int nk0 = k0 + 64;
            GLOAD16(Kg + (size_t)(nk0 + kr0) * D3 + ks0, KT(cur ^ 1) + t * 8);
            const u16* vr = Vg + (size_t)(nk0 + 2 * vi) * D3 + vsd;
            va = *(const u32x2*)vr;
            vb_ = *(const u32x2*)(vr + D3);
        }

        const int dq = qw - k0;     // multiple of 32

        if (dq >= 0) {
            const int two = (dq >= 32);

            // ---- QK^T ----
            f32x16 s0 = {}, s1 = {};
            __builtin_amdgcn_s_setprio(1);
#pragma unroll
            for (int c = 0; c < 4; ++c) {
                bf16x8 kf = *(const bf16x8*)(KT(cur) + q31 * 64 + (((2 * c + hi) ^ (q31 & 7)) << 3));
                s0 = __builtin_amdgcn_mfma_f32_32x32x16_bf16(kf, qf[c], s0, 0, 0, 0);
            }
            if (two) {
#pragma unroll
                for (int c = 0; c < 4; ++c) {
                    bf16x8 kf = *(const bf16x8*)(KT(cur) + (32 + q31) * 64 + (((2 * c + hi) ^ (q31 & 7)) << 3));
                    s1 = __builtin_amdgcn_mfma_f32_32x32x16_bf16(kf, qf[c], s1, 0, 0, 0);
                }
            }
            __builtin_amdgcn_s_setprio(0);

            // ---- causal boundary masks (wave-uniform branches) ----
            if (dq == 0) {
#pragma unroll
                for (int r = 0; r < 16; ++r) {
                    int krel = (r & 3) + 8 * (r >> 2) + 4 * hi;
                    if (krel > q31) s0[r] = -1e30f;
                }
            }
            if (dq == 32) {
#pragma unroll
                for (int r = 0; r < 16; ++r) {
                    int krel = (r & 3) + 8 * (r >> 2) + 4 * hi;
                    if (krel > q31) s1[r] = -1e30f;
                }
            }

            // ---- per-lane max (max3 trees) + defer-max fast path ----
            float a0 = F3(s0[0], s0[1], s0[2]);
            float a1 = F3(s0[3], s0[4], s0[5]);
            float a2 = F3(s0[6], s0[7], s0[8]);
            float a3 = F3(s0[9], s0[10], s0[11]);
            float a4 = F3(s0[12], s0[13], s0[14]);
            float lm = F3(F3(a0, a1, a2), a3, F3(a4, s0[15], -3.0e38f));
            if (two) {
                float b0 = F3(s1[0], s1[1], s1[2]);
                float b1 = F3(s1[3], s1[4], s1[5]);
                float b2 = F3(s1[6], s1[7], s1[8]);
                float b3 = F3(s1[9], s1[10], s1[11]);
                float b4 = F3(s1[12], s1[13], s1[14]);
                lm = fmaxf(lm, F3(F3(b0, b1, b2), b3, F3(b4, s1[15], -3.0e38f)));
            }

            if (!__all(lm <= m_ + 8.f)) {
                float pm = __shfl_xor(lm, 32);
                float vq = fmaxf(lm, pm);
                float newm = fmaxf(m_, vq);
                float corr = fexp2(m_ - newm);
                lacc[0] *= corr;
                o0 = o0 * corr;
                o1 = o1 * corr;
                m_ = newm;
            }

            // ---- exp + pack into bf16 word-pairs ----
            u32 wd0[4][2], wd1[4][2];
#pragma unroll
            for (int g = 0; g < 4; ++g) {
                float p0 = fexp2(s0[4 * g + 0] - m_);
                float p1 = fexp2(s0[4 * g + 1] - m_);
                float p2 = fexp2(s0[4 * g + 2] - m_);
                float p3 = fexp2(s0[4 * g + 3] - m_);
                wd0[g][0] = cvtpk_bf16(p0, p1);
                wd0[g][1] = cvtpk_bf16(p2, p3);
            }
            if (two) {
#pragma unroll
                for (int g = 0; g < 4; ++g) {
                    float p0 = fexp2(s1[4 * g + 0] - m_);
                    float p1 = fexp2(s1[4 * g + 1] - m_);
                    float p2 = fexp2(s1[4 * g + 2] - m_);
                    float p3 = fexp2(s1[4 * g + 3] - m_);
                    wd1[g][0] = cvtpk_bf16(p0, p1);
                    wd1[g][1] = cvtpk_bf16(p2, p3);
                }
            }

            // ---- P transpose via permlane32_swap + PV (+ ones-MFMA for l) ----
            __builtin_amdgcn_s_setprio(1);
#pragma unroll
            for (int c = 0; c < 2; ++c) {   // k 0..31
                u32 a0w = wd0[2 * c][0], a1w = wd0[2 * c][1];
                u32 b0w = wd0[2 * c + 1][0], b1w = wd0[2 * c + 1][1];
                asm("v_permlane32_swap_b32 %0, %1" : "+v"(a0w), "+v"(b0w));
                asm("v_permlane32_swap_b32 %0, %1" : "+v"(a1w), "+v"(b1w));
                union { u32x4 u; bf16x8 f; } pa;
                pa.u[0] = a0w; pa.u[1] = a1w; pa.u[2] = b0w; pa.u[3] = b1w;
                bf16x8 v0 = *(const bf16x8*)(VT(cur) + q31 * 64 + (((2 * c + hi) ^ (q31 & 7)) << 3));
                bf16x8 v1 = *(const bf16x8*)(VT(cur) + (32 + q31) * 64 + (((2 * c + hi) ^ (q31 & 7)) << 3));
                o0 = __builtin_amdgcn_mfma_f32_32x32x16_bf16(v0, pa.f, o0, 0, 0, 0);
                o1 = __builtin_amdgcn_mfma_f32_32x32x16_bf16(v1, pa.f, o1, 0, 0, 0);
                lacc = __builtin_amdgcn_mfma_f32_32x32x16_bf16(one_.f, pa.f, lacc, 0, 0, 0);
            }
            if (two) {
#pragma unroll
                for (int c = 0; c < 2; ++c) {   // k 32..63
                    u32 a0w = wd1[2 * c][0], a1w = wd1[2 * c][1];
                    u32 b0w = wd1[2 * c + 1][0], b1w = wd1[2 * c + 1][1];
                    asm("v_permlane32_swap_b32 %0, %1" : "+v"(a0w), "+v"(b0w));
                    asm("v_permlane32_swap_b32 %0, %1" : "+v"(a1w), "+v"(b1w));
                    union { u32x4 u; bf16x8 f; } pa;
                    pa.u[0] = a0w; pa.u[1] = a1w; pa.u[2] = b0w; pa.u[3] = b1w;
                    int ck = 2 * (c + 2) + hi;
                    bf16x8 v0 = *(const bf16x8*)(VT(cur) + q31 * 64 + ((ck ^ (q31 & 7)) << 3));
                    bf16x8 v1 = *(const bf16x8*)(VT(cur) + (32 + q31) * 64 + ((ck ^ (q31 & 7)) << 3));
                    o0 = __builtin_amdgcn_mfma_f32_32x32x16_bf16(v0, pa.f, o0, 0, 0, 0);
                    o1 = __builtin_amdgcn_mfma_f32_32x32x16_bf16(v1, pa.f, o1, 0, 0, 0);
                    lacc = __builtin_amdgcn_mfma_f32_32x32x16_bf16(one_.f, pa.f, lacc, 0, 0, 0);
                }
            }
            __builtin_amdgcn_s_setprio(0);
        }

        // ---- finish staging tile kt+1 ----
        if (havenext) {
            asm volatile("s_waitcnt vmcnt(0)" ::: "memory");
#pragma unroll
            for (int k = 0; k < 2; k++) {
                int d0 = vsd + 2 * k;
                u32 wlo = __builtin_amdgcn_perm(vb_[k], va[k], 0x05040100u);
                u32 whi = __builtin_amdgcn_perm(vb_[k], va[k], 0x07060302u);
                *(u32*)(VT(cur ^ 1) + d0 * 64 + ((vchunk ^ (d0 & 7)) << 3) + vcol) = wlo;
                *(u32*)(VT(cur ^ 1) + (d0 + 1) * 64 + ((vchunk ^ ((d0 + 1) & 7)) << 3) + vcol) = whi;
            }
        }
        __syncthreads();
        cur ^= 1;
    }

    // ---- epilogue: normalize, transpose O via LDS (8 wave-regions of 2048
    // u16, 64-u16 rows, chunk-swizzled; one-shot so conflicts negligible) ----
    float linv = 1.f / lacc[0];
    u16* Ep = SH + w * 2048;       // 32 rows x 64 u16 per wave, 8 waves = 16384
#pragma unroll
    for (int dt = 0; dt < 2; ++dt) {
#pragma unroll
        for (int g = 0; g < 4; ++g) {
#pragma unroll
            for (int s2 = 0; s2 < 2; ++s2) {
                float e0 = (dt ? o1[4 * g + 2 * s2] : o0[4 * g + 2 * s2]) * linv;
                float e1 = (dt ? o1[4 * g + 2 * s2 + 1] : o0[4 * g + 2 * s2 + 1]) * linv;
                u32 word = cvtpk_bf16(e0, e1);
                int chnk = 4 * dt + g;
                *(u32*)(Ep + q31 * 64 + ((chnk ^ (q31 & 7)) << 3) + 4 * hi + 2 * s2) = word;
            }
        }
    }
    asm volatile("s_waitcnt lgkmcnt(0)" ::: "memory");
    __builtin_amdgcn_sched_barrier(0);
    {
        int qp = lane >> 1;
        int dh = lane & 1;
        u16* yrow = y + (size_t)(b * Nn + qw + qp) * Dd + h * DHd + dh * 32;
#pragma unroll
        for (int cc = 0; cc < 4; ++cc) {
            int chnk = dh * 4 + cc;
            u32x4 vv = *(const u32x4*)(Ep + qp * 64 + ((chnk ^ (qp & 7)) << 3));
            *(u32x4*)(yrow + cc * 8) = vv;
        }
    }
#undef KT
#undef VT
}

extern "C" void kernel_launch(void* const* d_in, const int* in_sizes, int n_in,
                              void* d_out, int out_size, void* d_ws, size_t ws_size,
                              hipStream_t stream) {
    const float* x = (const float*)d_in[0];
    const float* Wqkv = (const float*)d_in[1];
    const float* Wout = (const float*)d_in[2];

    char* ws = (char*)d_ws;
    size_t off = 0;
    u16* xb = (u16*)(ws + off);    off += (size_t)Mm * Dd * 2;
    u16* wqkvb = (u16*)(ws + off); off += (size_t)D3 * Dd * 2;
    u16* woutb = (u16*)(ws + off); off += (size_t)Dd * Dd * 2;
    u16* qkv = (u16*)(ws + off);   off += (size_t)Mm * D3 * 2;
    u16* yb = (u16*)(ws + off);    off += (size_t)Mm * Dd * 2;

    const float SCL = 0.125f * 1.4426950408889634f;  // (1/sqrt(DH)) * log2(e)

    cvt_all<<<4096, 256, 0, stream>>>(x, Wqkv, Wout, xb, wqkvb, woutb, SCL);

    gemm_bt<0><<<dim3(D3 / 128, Mm / 128), 256, 0, stream>>>(xb, wqkvb, qkv, Mm, D3, Dd);
    attn<<<dim3(8, 64), 512, 0, stream>>>(qkv, yb);
    gemm_bt<1><<<dim3(Dd / 128, Mm / 128), 256, 0, stream>>>(yb, woutb, d_out, Mm, Dd, Dd);
}